// Round 8
// baseline (305.568 us; speedup 1.0000x reference)
//
#include <hip/hip_runtime.h>

#define H 1024
#define E 64
#define BT 64
#define THETA 1e-4f    // relative p-gap risk threshold

typedef __attribute__((ext_vector_type(4))) float f4;
typedef __attribute__((ext_vector_type(16))) float f32x16;
typedef __bf16 bf16x8 __attribute__((ext_vector_type(8)));
typedef unsigned int u32;
typedef __attribute__((ext_vector_type(4))) u32 u32x4;

__device__ __forceinline__ u32 cvtpk_bf16(float a, float b) {
    u32 r;
    asm("v_cvt_pk_bf16_f32 %0, %1, %2" : "=v"(r) : "v"(a), "v"(b));
    return r;
}
__device__ __forceinline__ float asfloat(u32 u) { union { u32 u; float f; } c; c.u = u; return c.f; }

// split 8 fp32 (k-ascending: a.xyzw, b.xyzw) into packed bf16-hi (RNE) and bf16-lo residual
__device__ __forceinline__ void split8(f4 a, f4 b, u32x4& hi, u32x4& lo) {
    float x0[4] = {a.x, a.z, b.x, b.z};
    float x1[4] = {a.y, a.w, b.y, b.w};
    #pragma unroll
    for (int i = 0; i < 4; ++i) {
        u32 h = cvtpk_bf16(x0[i], x1[i]);
        float r0 = x0[i] - asfloat(h << 16);
        float r1 = x1[i] - asfloat(h & 0xFFFF0000u);
        hi[i] = h;
        lo[i] = cvtpk_bf16(r0, r1);
    }
}

// async global->LDS, 16B per lane; LDS dest = wave-uniform base + lane*16
__device__ __forceinline__ void async16(const void* g, void* l) {
    __builtin_amdgcn_global_load_lds(
        (const __attribute__((address_space(1))) unsigned int*)g,
        (__attribute__((address_space(3))) unsigned int*)l,
        16, 0, 0);
}

// =====================================================================
// PROBE 1 — stage-only: R4's staging pipeline (A+B async16, 4 x 16 KB
// buffers, depth-3, counted vmcnt(4) + s_barrier per chunk), 64 chunks
// (2x the real kernel's staging volume), NO compute. If staging is the
// wall, this lands at ~2x R4's 65 us and shows in top-5.
// =====================================================================
__global__ __launch_bounds__(512, 4)
void gate_probe_stage(const float* __restrict__ hs, const float* __restrict__ wt,
                      unsigned int* __restrict__ scr, unsigned int scr_cap) {
    __shared__ float smem[16384];                 // 64 KB: 4 bufs x 16 KB
    const int t = threadIdx.x;
    const int wave = t >> 6;
    const int tok_base = blockIdx.x * BT;
    char* sb = (char*)smem;

    const int srow = t >> 3;
    const int srcj = (t & 7) ^ (srow & 7);
    const float* gA = hs + (size_t)(tok_base + srow) * H + srcj * 4;
    const float* gB = wt + (size_t)srow * H + srcj * 4;
    const int sdest = wave << 10;

    auto stage = [&](int c) {
        char* bb = sb + (c & 3) * 16384;
        async16(gA + (c & 31) * 32, bb + sdest);
        async16(gB + (c & 31) * 32, bb + 8192 + sdest);
    };

    stage(0); stage(1); stage(2);
    for (int c = 0; c < 64; ++c) {
        asm volatile("s_waitcnt vmcnt(4)" ::: "memory");
        __builtin_amdgcn_s_barrier();
        if (c < 61) stage(c + 3);
    }
    asm volatile("s_waitcnt vmcnt(0)" ::: "memory");
    __syncthreads();
    if (t == 0 && blockIdx.x < scr_cap)
        scr[blockIdx.x] = (unsigned int)smem[0];  // keepalive
}

// =====================================================================
// PROBE 2 — compute-only: R4's per-chunk compute (ds_read_b128 x4,
// split8 x2, 3 MFMA, s_barrier per chunk) on zeroed LDS, 64 chunks
// (2x real compute volume), NO global loads.
// =====================================================================
__global__ __launch_bounds__(512, 4)
void gate_probe_compute(float* __restrict__ scr, unsigned int scr_cap) {
    __shared__ float smem[16384];                 // 64 KB
    const int t = threadIdx.x;
    const int wave = t >> 6, lane = t & 63;
    char* sb = (char*)smem;
    for (int i = t; i < 16384; i += 512) smem[i] = 0.f;
    __syncthreads();

    const int lr = lane & 31, kh = lane >> 5;
    const int q4 = wave & 3, kh2 = wave >> 2;
    const int wrow = (q4 >> 1) * 32;
    const int wcol = (q4 & 1) * 32;
    const int arow = wrow + lr;
    const int s0 = kh2 * 4 + kh * 2;
    const int aoff = arow * 128 + ((s0 ^ (arow & 7)) << 4);
    const int boff = 8192 + (wcol + lr) * 128 + ((s0 ^ ((wcol + lr) & 7)) << 4);

    f32x16 acc0, acc1;
    #pragma unroll
    for (int i = 0; i < 16; ++i) { acc0[i] = 0.f; acc1[i] = 0.f; }

    for (int c = 0; c < 64; ++c) {
        asm volatile("s_waitcnt vmcnt(4)" ::: "memory");   // instant: mirrors instr stream
        __builtin_amdgcn_s_barrier();
        const char* cb = sb + (c & 3) * 16384;
        f4 a0 = *(const f4*)(cb + aoff);
        f4 a1 = *(const f4*)(cb + (aoff ^ 16));
        f4 b0 = *(const f4*)(cb + boff);
        f4 b1 = *(const f4*)(cb + (boff ^ 16));
        u32x4 ahp, alp, bhp, blp;
        split8(a0, a1, ahp, alp);
        split8(b0, b1, bhp, blp);
        const bf16x8 ah = __builtin_bit_cast(bf16x8, ahp);
        const bf16x8 al = __builtin_bit_cast(bf16x8, alp);
        const bf16x8 bh = __builtin_bit_cast(bf16x8, bhp);
        const bf16x8 bl = __builtin_bit_cast(bf16x8, blp);
        acc0 = __builtin_amdgcn_mfma_f32_32x32x16_bf16(ah, bh, acc0, 0, 0, 0);
        acc1 = __builtin_amdgcn_mfma_f32_32x32x16_bf16(ah, bl, acc1, 0, 0, 0);
        acc1 = __builtin_amdgcn_mfma_f32_32x32x16_bf16(al, bh, acc1, 0, 0, 0);
    }
    float s = 0.f;
    #pragma unroll
    for (int i = 0; i < 16; ++i) s += acc0[i] + acc1[i];
    const unsigned int idx = blockIdx.x * 8 + wave;
    if (lane == 0 && idx < scr_cap) scr[idx] = s;  // keepalive
}

// =====================================================================
// Pass A — EXACT round-4 structure (best measured: 8 waves, 2 blocks/CU,
// 4 LDS buffers, depth-3 counted-vmcnt pipeline, A+B staged).
// =====================================================================
__global__ __launch_bounds__(512, 4)
void gate_main(const float* __restrict__ hs, const float* __restrict__ wt,
               float* __restrict__ out, float* __restrict__ pi_ws,
               float* __restrict__ ce_ws, unsigned int* __restrict__ risk_cnt,
               unsigned int* __restrict__ risk_list, unsigned int risk_cap,
               int n_tokens) {
    __shared__ float smem[16384];                 // 64 KB
    const int t = threadIdx.x;
    const int wave = t >> 6, lane = t & 63;
    const int tok_base = blockIdx.x * BT;
    char* sb = (char*)smem;

    const int srow = t >> 3;                      // 0..63
    const int srcj = (t & 7) ^ (srow & 7);
    const float* gA = hs + (size_t)(tok_base + srow) * H + srcj * 4;
    const float* gB = wt + (size_t)srow * H + srcj * 4;
    const int sdest = wave << 10;

    const int lr = lane & 31, kh = lane >> 5;
    const int q4 = wave & 3, kh2 = wave >> 2;
    const int wrow = (q4 >> 1) * 32;
    const int wcol = (q4 & 1) * 32;
    const int arow = wrow + lr, brow = wcol + lr;
    const int s0 = kh2 * 4 + kh * 2;
    const int aoff = arow * 128 + ((s0 ^ (arow & 7)) << 4);
    const int boff = 8192 + brow * 128 + ((s0 ^ (brow & 7)) << 4);

    f32x16 acc0, acc1;
    #pragma unroll
    for (int i = 0; i < 16; ++i) { acc0[i] = 0.f; acc1[i] = 0.f; }

    auto stage = [&](int c) {
        char* bb = sb + (c & 3) * 16384;
        async16(gA + c * 32, bb + sdest);
        async16(gB + c * 32, bb + 8192 + sdest);
    };
    auto compute = [&](int c) {
        const char* cb = sb + (c & 3) * 16384;
        f4 a0 = *(const f4*)(cb + aoff);
        f4 a1 = *(const f4*)(cb + (aoff ^ 16));
        f4 b0 = *(const f4*)(cb + boff);
        f4 b1 = *(const f4*)(cb + (boff ^ 16));
        u32x4 ahp, alp, bhp, blp;
        split8(a0, a1, ahp, alp);
        split8(b0, b1, bhp, blp);
        const bf16x8 ah = __builtin_bit_cast(bf16x8, ahp);
        const bf16x8 al = __builtin_bit_cast(bf16x8, alp);
        const bf16x8 bh = __builtin_bit_cast(bf16x8, bhp);
        const bf16x8 bl = __builtin_bit_cast(bf16x8, blp);
        acc0 = __builtin_amdgcn_mfma_f32_32x32x16_bf16(ah, bh, acc0, 0, 0, 0);
        acc1 = __builtin_amdgcn_mfma_f32_32x32x16_bf16(ah, bl, acc1, 0, 0, 0);
        acc1 = __builtin_amdgcn_mfma_f32_32x32x16_bf16(al, bh, acc1, 0, 0, 0);
    };

    stage(0); stage(1); stage(2);
    for (int c = 0; c < 30; ++c) {
        asm volatile("s_waitcnt vmcnt(4)" ::: "memory");
        __builtin_amdgcn_s_barrier();
        __builtin_amdgcn_sched_barrier(0);
        if (c < 29) stage(c + 3);
        __builtin_amdgcn_sched_barrier(0);
        compute(c);
    }
    asm volatile("s_waitcnt vmcnt(2)" ::: "memory");
    __builtin_amdgcn_s_barrier();
    __builtin_amdgcn_sched_barrier(0);
    compute(30);
    asm volatile("s_waitcnt vmcnt(0)" ::: "memory");
    __builtin_amdgcn_s_barrier();
    __builtin_amdgcn_sched_barrier(0);
    compute(31);
    __syncthreads();

    float* S = smem;
    f4* S4 = (f4*)smem;
    float* P2    = smem + 4352;                   // [4][32][32] K-half partials
    float* recip = smem + 8448;
    float* hist  = smem + 8512;
    float* pi7   = smem + 8576;                   // [7][64]

    {
        float vs[16];
        #pragma unroll
        for (int i = 0; i < 16; ++i) vs[i] = acc0[i] + acc1[i];
        if (kh2) {
            #pragma unroll
            for (int gq = 0; gq < 4; ++gq)
                #pragma unroll
                for (int qq = 0; qq < 4; ++qq)
                    P2[q4 * 1024 + (qq + gq * 8 + kh * 4) * 32 + lr] = vs[gq * 4 + qq];
        }
        if (t < 64) hist[t] = 0.f;
        __syncthreads();
        if (!kh2) {
            #pragma unroll
            for (int gq = 0; gq < 4; ++gq)
                #pragma unroll
                for (int qq = 0; qq < 4; ++qq) {
                    const int row = qq + gq * 8 + kh * 4;   // C/D layout (m74/m101)
                    S[(wrow + row) * 68 + wcol + lr] =
                        vs[gq * 4 + qq] + P2[q4 * 1024 + row * 32 + lr];
                }
        }
    }
    __syncthreads();

    if (t < 256) {
        const int tok = t >> 2, q = t & 3;
        f4 v[4];
        #pragma unroll
        for (int c2 = 0; c2 < 4; ++c2) v[c2] = S4[tok * 17 + q * 4 + c2];
        float m = v[0].x;
        #pragma unroll
        for (int c2 = 0; c2 < 4; ++c2)
            m = fmaxf(m, fmaxf(fmaxf(v[c2].x, v[c2].y), fmaxf(v[c2].z, v[c2].w)));
        m = fmaxf(m, __shfl_xor(m, 1, 64));
        m = fmaxf(m, __shfl_xor(m, 2, 64));
        float lsum = 0.f;
        #pragma unroll
        for (int c2 = 0; c2 < 4; ++c2) {
            v[c2].x = __expf(v[c2].x - m); v[c2].y = __expf(v[c2].y - m);
            v[c2].z = __expf(v[c2].z - m); v[c2].w = __expf(v[c2].w - m);
            lsum += (v[c2].x + v[c2].y) + (v[c2].z + v[c2].w);
        }
        #pragma unroll
        for (int c2 = 0; c2 < 4; ++c2) S4[tok * 17 + q * 4 + c2] = v[c2];
        lsum += __shfl_xor(lsum, 1, 64);
        lsum += __shfl_xor(lsum, 2, 64);
        if (q == 0) recip[tok] = 1.0f / lsum;
    }
    __syncthreads();

    const int selw = blockIdx.x & 7;
    if (wave == selw) {
        const int tok = lane;
        const int tok_g = tok_base + tok;
        float val[9]; int idx[9];
        #pragma unroll
        for (int r = 0; r < 9; ++r) { val[r] = -1.f; idx[r] = 0; }
        #pragma unroll
        for (int c2 = 0; c2 < 16; ++c2) {
            f4 v = S4[tok * 17 + c2];
            float e4[4] = {v.x, v.y, v.z, v.w};
            #pragma unroll
            for (int u = 0; u < 4; ++u) {
                float cv = e4[u]; int ci = c2 * 4 + u;
                #pragma unroll
                for (int r = 0; r < 9; ++r) {
                    const bool g = cv > val[r];    // strict: stream order = stable ties
                    const float tv = val[r]; const int ti = idx[r];
                    val[r] = g ? cv : tv;  idx[r] = g ? ci : ti;
                    cv = g ? tv : cv;      ci = g ? ti : ci;
                }
            }
        }
        const float s8 = ((val[0] + val[1]) + (val[2] + val[3]))
                       + ((val[4] + val[5]) + (val[6] + val[7]));
        const float wsum = s8 + 1e-20f;
        f4* out4 = (f4*)out;
        f4 o;
        o.x = (float)idx[0]; o.y = (float)idx[1]; o.z = (float)idx[2]; o.w = (float)idx[3];
        out4[(size_t)tok_g * 2] = o;
        o.x = (float)idx[4]; o.y = (float)idx[5]; o.z = (float)idx[6]; o.w = (float)idx[7];
        out4[(size_t)tok_g * 2 + 1] = o;
        const size_t wb = (size_t)n_tokens * 2;
        o.x = val[0] / wsum; o.y = val[1] / wsum; o.z = val[2] / wsum; o.w = val[3] / wsum;
        out4[wb + (size_t)tok_g * 2] = o;
        o.x = val[4] / wsum; o.y = val[5] / wsum; o.z = val[6] / wsum; o.w = val[7] / wsum;
        out4[wb + (size_t)tok_g * 2 + 1] = o;
        #pragma unroll
        for (int r = 0; r < 8; ++r) atomicAdd(&hist[idx[r]], 1.0f);
        float ming = 1e30f;
        #pragma unroll
        for (int r = 0; r < 8; ++r)
            ming = fminf(ming, (val[r] - val[r + 1]) / fmaxf(val[r], 1e-30f));
        if (ming < THETA) {
            unsigned int pos = atomicAdd(risk_cnt, 1u);
            if (pos < risk_cap) risk_list[pos] = (unsigned int)tok_g;
        }
    } else {
        const int sev = ((wave - selw) & 7) - 1;          // 0..6
        const int e = lane;
        const int t0 = sev * 9;
        const int t1 = (sev == 6) ? 64 : (t0 + 9);
        float part = 0.f;
        for (int tok = t0; tok < t1; ++tok)
            part = fmaf(S[tok * 68 + e], recip[tok], part);
        pi7[sev * 64 + e] = part;
    }
    __syncthreads();
    const int rep = (blockIdx.x & 7) << 6;
    if (t < 64) {
        const float p = ((pi7[t] + pi7[64 + t]) + (pi7[128 + t] + pi7[192 + t]))
                      + ((pi7[256 + t] + pi7[320 + t]) + pi7[384 + t]);
        atomicAdd(&pi_ws[rep + t], p);
    } else if (t < 128) {
        atomicAdd(&ce_ws[rep + (t - 64)], hist[t - 64]);
    }
}

// =====================================================================
// Pass B: fp64 recompute of risky tokens; block 0 finalizes aux loss.
// =====================================================================
__global__ __launch_bounds__(256)
void gate_fixup(const float* __restrict__ hs, const float* __restrict__ wt,
                float* __restrict__ out, const unsigned int* __restrict__ risk_cnt,
                const unsigned int* __restrict__ risk_list, unsigned int risk_cap,
                int n_tokens, const float* __restrict__ pi_ws,
                const float* __restrict__ ce_ws) {
    __shared__ float hrow[H];
    __shared__ double red[256];
    const int t = threadIdx.x;

    if (blockIdx.x == 0 && t < 64) {
        double pi = 0.0, ce = 0.0;
        #pragma unroll
        for (int rp = 0; rp < 8; ++rp) {
            pi += (double)pi_ws[rp * 64 + t];
            ce += (double)ce_ws[rp * 64 + t];
        }
        pi /= (double)n_tokens;
        ce /= ((double)n_tokens * 8.0);
        double term = pi * ce * 64.0;
        #pragma unroll
        for (int off = 32; off > 0; off >>= 1) term += __shfl_xor(term, off, 64);
        if (t == 0) out[(size_t)n_tokens * 16] = (float)(term * 0.01);
    }

    unsigned int cnt = *risk_cnt;
    if (cnt > risk_cap) cnt = risk_cap;

    for (unsigned int u = blockIdx.x; u < cnt; u += gridDim.x) {
        const int tok = (int)risk_list[u];
        ((float4*)hrow)[t] = ((const float4*)(hs + (size_t)tok * H))[t];
        __syncthreads();

        const int e = t >> 2, sl = t & 3;
        const float4* wp = (const float4*)wt + (size_t)e * 256;
        const float4* hp = (const float4*)hrow;
        double acc = 0.0;
        #pragma unroll 8
        for (int k4 = 0; k4 < 64; ++k4) {
            float4 wv = wp[k4 * 4 + sl];
            float4 hv = hp[k4 * 4 + sl];
            acc = fma((double)wv.x, (double)hv.x, acc);
            acc = fma((double)wv.y, (double)hv.y, acc);
            acc = fma((double)wv.z, (double)hv.z, acc);
            acc = fma((double)wv.w, (double)hv.w, acc);
        }
        red[t] = acc;
        __syncthreads();

        if (t < 64) {
            const int lane = t;
            double lg = red[t * 4] + red[t * 4 + 1] + red[t * 4 + 2] + red[t * 4 + 3];
            double m = lg;
            #pragma unroll
            for (int off = 32; off > 0; off >>= 1) {
                double o = __shfl_xor(m, off, 64);
                m = (o > m) ? o : m;
            }
            const double p = exp(lg - m);
            double v = lg, psum = 0.0, mypv = 0.0;
            int myidx = 0;
            for (int r = 0; r < 8; ++r) {
                double bv = v; int bi = lane;
                #pragma unroll
                for (int off = 32; off > 0; off >>= 1) {
                    double ov = __shfl_xor(bv, off, 64);
                    int    oi = __shfl_xor(bi, off, 64);
                    if (ov > bv || (ov == bv && oi < bi)) { bv = ov; bi = oi; }
                }
                double pw = __shfl(p, bi, 64);
                psum += pw;
                if (lane == r) { myidx = bi; mypv = pw; }
                if (lane == bi) v = -1e300;
            }
            const double wsum = psum + 1e-20;
            if (lane < 8) {
                out[(size_t)tok * 8 + lane] = (float)myidx;
                out[(size_t)n_tokens * 8 + (size_t)tok * 8 + lane] = (float)(mypv / wsum);
            }
        }
        __syncthreads();
    }
}

extern "C" void kernel_launch(void* const* d_in, const int* in_sizes, int n_in,
                              void* d_out, int out_size, void* d_ws, size_t ws_size,
                              hipStream_t stream) {
    const float* hs = (const float*)d_in[0];
    const float* wt = (const float*)d_in[1];
    float* out = (float*)d_out;
    const int n_tokens = in_sizes[0] / H;         // 32768

    // ws layout: pi[8][64] @0 (2048B), ce[8][64] @2048, risk_cnt @4096,
    //            risk_list @4608
    float* pi_ws = (float*)d_ws;
    float* ce_ws = (float*)((char*)d_ws + 2048);
    unsigned int* risk_cnt  = (unsigned int*)((char*)d_ws + 4096);
    unsigned int* risk_list = (unsigned int*)((char*)d_ws + 4608);
    unsigned int risk_cap = (unsigned int)((ws_size > 4608 ? (ws_size - 4608) : 0) / 4);
    if (risk_cap > (unsigned int)n_tokens) risk_cap = (unsigned int)n_tokens;

    // ---- diagnostic probes (scribble into risk_list region, PRE-memset;
    //      real pipeline only ever reads risk_list[0, cnt) which it writes) ----
    gate_probe_stage<<<n_tokens / BT, 512, 0, stream>>>(hs, wt, risk_list, risk_cap);
    gate_probe_compute<<<n_tokens / BT, 512, 0, stream>>>((float*)risk_list, risk_cap);

    size_t zbytes = ws_size < 4608 ? ws_size : 4608;
    hipMemsetAsync(d_ws, 0, zbytes, stream);

    gate_main<<<n_tokens / BT, 512, 0, stream>>>(hs, wt, out, pi_ws, ce_ws,
                                                 risk_cnt, risk_list, risk_cap, n_tokens);
    gate_fixup<<<256, 256, 0, stream>>>(hs, wt, out, risk_cnt, risk_list, risk_cap,
                                        n_tokens, pi_ws, ce_ws);
}

// Round 9
// 269.995 us; speedup vs baseline: 1.1318x; 1.1318x over previous
//
#include <hip/hip_runtime.h>

#define H 1024
#define E 64
#define BT 64
#define THETA 1e-4f    // relative p-gap risk threshold

typedef __attribute__((ext_vector_type(4))) float f4;
typedef __attribute__((ext_vector_type(16))) float f32x16;
typedef __bf16 bf16x8 __attribute__((ext_vector_type(8)));
typedef unsigned int u32;
typedef __attribute__((ext_vector_type(4))) u32 u32x4;

__device__ __forceinline__ u32 cvtpk_bf16(float a, float b) {
    u32 r;
    asm("v_cvt_pk_bf16_f32 %0, %1, %2" : "=v"(r) : "v"(a), "v"(b));
    return r;
}
__device__ __forceinline__ float asfloat(u32 u) { union { u32 u; float f; } c; c.u = u; return c.f; }

// split 8 fp32 (k-ascending: a.xyzw, b.xyzw) into packed bf16-hi (RNE) and bf16-lo residual
__device__ __forceinline__ void split8(f4 a, f4 b, u32x4& hi, u32x4& lo) {
    float x0[4] = {a.x, a.z, b.x, b.z};
    float x1[4] = {a.y, a.w, b.y, b.w};
    #pragma unroll
    for (int i = 0; i < 4; ++i) {
        u32 h = cvtpk_bf16(x0[i], x1[i]);
        float r0 = x0[i] - asfloat(h << 16);
        float r1 = x1[i] - asfloat(h & 0xFFFF0000u);
        hi[i] = h;
        lo[i] = cvtpk_bf16(r0, r1);
    }
}

// async global->LDS, 16B per lane; LDS dest = wave-uniform base + lane*16,
// GLOBAL source is per-lane.
__device__ __forceinline__ void async16(const void* g, void* l) {
    __builtin_amdgcn_global_load_lds(
        (const __attribute__((address_space(1))) unsigned int*)g,
        (__attribute__((address_space(3))) unsigned int*)l,
        16, 0, 0);
}

// =====================================================================
// Pass A (round 9): BARRIER-FREE K-loop. 64 tok x 64 exp per block,
// 512 threads = 8 waves (4 quadrants x 2 K-halves), 2 blocks/CU.
// R8 ablation: staging-only ~27 us (= HBM/L2 floor), compute-only
// ~13 us, composed (barriered) 65 us -> ~25 us of convoy slack from the
// per-chunk 16-wave rendezvous. Fix: WAVE-PRIVATE staging - each wave
// stages exactly the 4 KB/chunk it consumes (2 async16 for A: 64 lanes
// enumerate (row=lane&31, slot=kh2*4+(lane>>5)+2i); 2 for B) into its
// own 8 KB LDS slice (2 buffers, depth-1 prefetch, own counted
// vmcnt(4)). NO s_barrier in the loop; one __syncthreads before the
// tail. A/B staged 2x (wave-pair dup) but dup is L2-hot. Linear LDS
// layout (no swizzle): 32-lane contiguous 512 B b128 reads are
// conflict-free; kh halves hit disjoint 1 KB regions.
// LDS: wave w at w*8192: buf q=(c&1)*4096: A0 @0, A1 @1024, B0 @2048,
// B1 @3072. Tail overlay (after sync): S[64][68] @f0, P2 @f4352,
// recip @f8448, hist @f8512, pi7 @f8576.
// =====================================================================
__global__ __launch_bounds__(512, 4)
void gate_main(const float* __restrict__ hs, const float* __restrict__ wt,
               float* __restrict__ out, float* __restrict__ pi_ws,
               float* __restrict__ ce_ws, unsigned int* __restrict__ risk_cnt,
               unsigned int* __restrict__ risk_list, unsigned int risk_cap,
               int n_tokens) {
    __shared__ float smem[16384];                 // 64 KB: 8 waves x 8 KB
    const int t = threadIdx.x;
    const int wave = t >> 6, lane = t & 63;
    const int tok_base = blockIdx.x * BT;
    char* sb = (char*)smem;

    // ---- wave roles: quadrant (q4) x K-half (kh2); lane split lr/kh
    const int lr = lane & 31, kh = lane >> 5;
    const int q4 = wave & 3, kh2 = wave >> 2;
    const int wrow = (q4 >> 1) * 32;              // token base of quadrant
    const int wcol = (q4 & 1) * 32;               // expert base of quadrant

    // ---- private staging sources: lane -> (row = lr, slotpair i)
    //      slot(i) = kh2*4 + (lane>>5) + 2i ; addr advances c*32 floats/chunk
    const float* pA0 = hs + (size_t)(tok_base + wrow + lr) * H + (kh2 * 4 + kh) * 4;
    const float* pA1 = pA0 + 8;                   // slots +2
    const float* pB0 = wt + (size_t)(wcol + lr) * H + (kh2 * 4 + kh) * 4;
    const float* pB1 = pB0 + 8;
    char* wb = sb + wave * 8192;                  // wave-private 8 KB

    // ---- private fragment read offsets (linear, conflict-free)
    const int ra = kh * 1024 + lr * 16;           // a0; a1 = +512
    const int rb = 2048 + ra;                     // b0; b1 = +512

    f32x16 acc0, acc1;
    #pragma unroll
    for (int i = 0; i < 16; ++i) { acc0[i] = 0.f; acc1[i] = 0.f; }

    auto stage = [&](int c) {                     // 4 async16, wave-private dest
        char* bb = wb + (c & 1) * 4096;
        async16(pA0 + c * 32, bb);
        async16(pA1 + c * 32, bb + 1024);
        async16(pB0 + c * 32, bb + 2048);
        async16(pB1 + c * 32, bb + 3072);
    };

    // ---- prologue: chunks 0,1 in flight (8 loads)
    stage(0); stage(1);

    for (int c = 0; c < 32; ++c) {
        // retire own chunk c (keep c+1's 4 loads in flight); no barrier
        if (c < 31) { asm volatile("s_waitcnt vmcnt(4)" ::: "memory"); }
        else        { asm volatile("s_waitcnt vmcnt(0)" ::: "memory"); }
        __builtin_amdgcn_sched_barrier(0);
        const char* bb = wb + (c & 1) * 4096;
        f4 a0 = *(const f4*)(bb + ra);
        f4 a1 = *(const f4*)(bb + ra + 512);
        f4 b0 = *(const f4*)(bb + rb);
        f4 b1 = *(const f4*)(bb + rb + 512);
        __builtin_amdgcn_sched_barrier(0);        // pin reads before re-stage
        if (c + 2 < 32) stage(c + 2);             // overwrites buf c&1: reads above
                                                  // complete ~120cy, write lands ~900cy
        u32x4 ahp, alp, bhp, blp;
        split8(a0, a1, ahp, alp);
        split8(b0, b1, bhp, blp);
        const bf16x8 ah = __builtin_bit_cast(bf16x8, ahp);
        const bf16x8 al = __builtin_bit_cast(bf16x8, alp);
        const bf16x8 bh = __builtin_bit_cast(bf16x8, bhp);
        const bf16x8 bl = __builtin_bit_cast(bf16x8, blp);
        acc0 = __builtin_amdgcn_mfma_f32_32x32x16_bf16(ah, bh, acc0, 0, 0, 0);
        acc1 = __builtin_amdgcn_mfma_f32_32x32x16_bf16(ah, bl, acc1, 0, 0, 0);
        acc1 = __builtin_amdgcn_mfma_f32_32x32x16_bf16(al, bh, acc1, 0, 0, 0);
    }
    __syncthreads();                              // single rendezvous before tail

    float* S = smem;
    f4* S4 = (f4*)smem;
    float* P2    = smem + 4352;                   // [4][32][32] K-half partials
    float* recip = smem + 8448;
    float* hist  = smem + 8512;
    float* pi7   = smem + 8576;                   // [7][64]

    // ---- combine K-half partials, write logits S[64][68] ----
    {
        float vs[16];
        #pragma unroll
        for (int i = 0; i < 16; ++i) vs[i] = acc0[i] + acc1[i];
        if (kh2) {
            #pragma unroll
            for (int gq = 0; gq < 4; ++gq)
                #pragma unroll
                for (int qq = 0; qq < 4; ++qq)
                    P2[q4 * 1024 + (qq + gq * 8 + kh * 4) * 32 + lr] = vs[gq * 4 + qq];
        }
        if (t < 64) hist[t] = 0.f;
        __syncthreads();
        if (!kh2) {
            #pragma unroll
            for (int gq = 0; gq < 4; ++gq)
                #pragma unroll
                for (int qq = 0; qq < 4; ++qq) {
                    const int row = qq + gq * 8 + kh * 4;   // C/D layout (m74/m101)
                    S[(wrow + row) * 68 + wcol + lr] =
                        vs[gq * 4 + qq] + P2[q4 * 1024 + row * 32 + lr];
                }
        }
    }
    __syncthreads();

    // ---- p = exp(l - m) in-place, 4 threads per token (threads 0..255) ----
    if (t < 256) {
        const int tok = t >> 2, q = t & 3;
        f4 v[4];
        #pragma unroll
        for (int c2 = 0; c2 < 4; ++c2) v[c2] = S4[tok * 17 + q * 4 + c2];
        float m = v[0].x;
        #pragma unroll
        for (int c2 = 0; c2 < 4; ++c2)
            m = fmaxf(m, fmaxf(fmaxf(v[c2].x, v[c2].y), fmaxf(v[c2].z, v[c2].w)));
        m = fmaxf(m, __shfl_xor(m, 1, 64));
        m = fmaxf(m, __shfl_xor(m, 2, 64));
        float lsum = 0.f;
        #pragma unroll
        for (int c2 = 0; c2 < 4; ++c2) {
            v[c2].x = __expf(v[c2].x - m); v[c2].y = __expf(v[c2].y - m);
            v[c2].z = __expf(v[c2].z - m); v[c2].w = __expf(v[c2].w - m);
            lsum += (v[c2].x + v[c2].y) + (v[c2].z + v[c2].w);
        }
        #pragma unroll
        for (int c2 = 0; c2 < 4; ++c2) S4[tok * 17 + q * 4 + c2] = v[c2];
        lsum += __shfl_xor(lsum, 1, 64);
        lsum += __shfl_xor(lsum, 2, 64);
        if (q == 0) recip[tok] = 1.0f / lsum;
    }
    __syncthreads();

    // ---- SEL (one wave, thread-per-token) + pi partials (other 7 waves) ----
    const int selw = blockIdx.x & 7;
    if (wave == selw) {
        const int tok = lane;
        const int tok_g = tok_base + tok;
        float val[9]; int idx[9];
        #pragma unroll
        for (int r = 0; r < 9; ++r) { val[r] = -1.f; idx[r] = 0; }
        #pragma unroll
        for (int c2 = 0; c2 < 16; ++c2) {
            f4 v = S4[tok * 17 + c2];
            float e4[4] = {v.x, v.y, v.z, v.w};
            #pragma unroll
            for (int u = 0; u < 4; ++u) {
                float cv = e4[u]; int ci = c2 * 4 + u;
                #pragma unroll
                for (int r = 0; r < 9; ++r) {
                    const bool g = cv > val[r];    // strict: stream order = stable ties
                    const float tv = val[r]; const int ti = idx[r];
                    val[r] = g ? cv : tv;  idx[r] = g ? ci : ti;
                    cv = g ? tv : cv;      ci = g ? ti : ci;
                }
            }
        }
        const float s8 = ((val[0] + val[1]) + (val[2] + val[3]))
                       + ((val[4] + val[5]) + (val[6] + val[7]));
        const float wsum = s8 + 1e-20f;
        f4* out4 = (f4*)out;
        f4 o;
        o.x = (float)idx[0]; o.y = (float)idx[1]; o.z = (float)idx[2]; o.w = (float)idx[3];
        out4[(size_t)tok_g * 2] = o;
        o.x = (float)idx[4]; o.y = (float)idx[5]; o.z = (float)idx[6]; o.w = (float)idx[7];
        out4[(size_t)tok_g * 2 + 1] = o;
        const size_t wb2 = (size_t)n_tokens * 2;
        o.x = val[0] / wsum; o.y = val[1] / wsum; o.z = val[2] / wsum; o.w = val[3] / wsum;
        out4[wb2 + (size_t)tok_g * 2] = o;
        o.x = val[4] / wsum; o.y = val[5] / wsum; o.z = val[6] / wsum; o.w = val[7] / wsum;
        out4[wb2 + (size_t)tok_g * 2 + 1] = o;
        #pragma unroll
        for (int r = 0; r < 8; ++r) atomicAdd(&hist[idx[r]], 1.0f);
        float ming = 1e30f;
        #pragma unroll
        for (int r = 0; r < 8; ++r)
            ming = fminf(ming, (val[r] - val[r + 1]) / fmaxf(val[r], 1e-30f));
        if (ming < THETA) {
            unsigned int pos = atomicAdd(risk_cnt, 1u);
            if (pos < risk_cap) risk_list[pos] = (unsigned int)tok_g;
        }
    } else {
        const int sev = ((wave - selw) & 7) - 1;          // 0..6
        const int e = lane;
        const int t0 = sev * 9;
        const int t1 = (sev == 6) ? 64 : (t0 + 9);
        float part = 0.f;
        for (int tok = t0; tok < t1; ++tok)
            part = fmaf(S[tok * 68 + e], recip[tok], part);
        pi7[sev * 64 + e] = part;
    }
    __syncthreads();
    // ---- 8-replica accumulators: atomic contention / 8 ----
    const int rep = (blockIdx.x & 7) << 6;
    if (t < 64) {
        const float p = ((pi7[t] + pi7[64 + t]) + (pi7[128 + t] + pi7[192 + t]))
                      + ((pi7[256 + t] + pi7[320 + t]) + pi7[384 + t]);
        atomicAdd(&pi_ws[rep + t], p);
    } else if (t < 128) {
        atomicAdd(&ce_ws[rep + (t - 64)], hist[t - 64]);
    }
}

// =====================================================================
// Pass B: fp64 recompute of risky tokens; block 0 finalizes aux loss.
// =====================================================================
__global__ __launch_bounds__(256)
void gate_fixup(const float* __restrict__ hs, const float* __restrict__ wt,
                float* __restrict__ out, const unsigned int* __restrict__ risk_cnt,
                const unsigned int* __restrict__ risk_list, unsigned int risk_cap,
                int n_tokens, const float* __restrict__ pi_ws,
                const float* __restrict__ ce_ws) {
    __shared__ float hrow[H];
    __shared__ double red[256];
    const int t = threadIdx.x;

    if (blockIdx.x == 0 && t < 64) {
        double pi = 0.0, ce = 0.0;
        #pragma unroll
        for (int rp = 0; rp < 8; ++rp) {
            pi += (double)pi_ws[rp * 64 + t];
            ce += (double)ce_ws[rp * 64 + t];
        }
        pi /= (double)n_tokens;
        ce /= ((double)n_tokens * 8.0);
        double term = pi * ce * 64.0;
        #pragma unroll
        for (int off = 32; off > 0; off >>= 1) term += __shfl_xor(term, off, 64);
        if (t == 0) out[(size_t)n_tokens * 16] = (float)(term * 0.01);
    }

    unsigned int cnt = *risk_cnt;
    if (cnt > risk_cap) cnt = risk_cap;

    for (unsigned int u = blockIdx.x; u < cnt; u += gridDim.x) {
        const int tok = (int)risk_list[u];
        ((float4*)hrow)[t] = ((const float4*)(hs + (size_t)tok * H))[t];
        __syncthreads();

        const int e = t >> 2, sl = t & 3;
        const float4* wp = (const float4*)wt + (size_t)e * 256;
        const float4* hp = (const float4*)hrow;
        double acc = 0.0;
        #pragma unroll 8
        for (int k4 = 0; k4 < 64; ++k4) {
            float4 wv = wp[k4 * 4 + sl];
            float4 hv = hp[k4 * 4 + sl];
            acc = fma((double)wv.x, (double)hv.x, acc);
            acc = fma((double)wv.y, (double)hv.y, acc);
            acc = fma((double)wv.z, (double)hv.z, acc);
            acc = fma((double)wv.w, (double)hv.w, acc);
        }
        red[t] = acc;
        __syncthreads();

        if (t < 64) {
            const int lane = t;
            double lg = red[t * 4] + red[t * 4 + 1] + red[t * 4 + 2] + red[t * 4 + 3];
            double m = lg;
            #pragma unroll
            for (int off = 32; off > 0; off >>= 1) {
                double o = __shfl_xor(m, off, 64);
                m = (o > m) ? o : m;
            }
            const double p = exp(lg - m);
            double v = lg, psum = 0.0, mypv = 0.0;
            int myidx = 0;
            for (int r = 0; r < 8; ++r) {
                double bv = v; int bi = lane;
                #pragma unroll
                for (int off = 32; off > 0; off >>= 1) {
                    double ov = __shfl_xor(bv, off, 64);
                    int    oi = __shfl_xor(bi, off, 64);
                    if (ov > bv || (ov == bv && oi < bi)) { bv = ov; bi = oi; }
                }
                double pw = __shfl(p, bi, 64);
                psum += pw;
                if (lane == r) { myidx = bi; mypv = pw; }
                if (lane == bi) v = -1e300;
            }
            const double wsum = psum + 1e-20;
            if (lane < 8) {
                out[(size_t)tok * 8 + lane] = (float)myidx;
                out[(size_t)n_tokens * 8 + (size_t)tok * 8 + lane] = (float)(mypv / wsum);
            }
        }
        __syncthreads();
    }
}

extern "C" void kernel_launch(void* const* d_in, const int* in_sizes, int n_in,
                              void* d_out, int out_size, void* d_ws, size_t ws_size,
                              hipStream_t stream) {
    const float* hs = (const float*)d_in[0];
    const float* wt = (const float*)d_in[1];
    float* out = (float*)d_out;
    const int n_tokens = in_sizes[0] / H;         // 32768

    // ws layout: pi[8][64] @0 (2048B), ce[8][64] @2048, risk_cnt @4096,
    //            risk_list @4608
    float* pi_ws = (float*)d_ws;
    float* ce_ws = (float*)((char*)d_ws + 2048);
    unsigned int* risk_cnt  = (unsigned int*)((char*)d_ws + 4096);
    unsigned int* risk_list = (unsigned int*)((char*)d_ws + 4608);
    unsigned int risk_cap = (unsigned int)((ws_size > 4608 ? (ws_size - 4608) : 0) / 4);
    if (risk_cap > (unsigned int)n_tokens) risk_cap = (unsigned int)n_tokens;

    size_t zbytes = ws_size < 4608 ? ws_size : 4608;
    hipMemsetAsync(d_ws, 0, zbytes, stream);

    gate_main<<<n_tokens / BT, 512, 0, stream>>>(hs, wt, out, pi_ws, ce_ws,
                                                 risk_cnt, risk_list, risk_cap, n_tokens);
    gate_fixup<<<256, 256, 0, stream>>>(hs, wt, out, risk_cnt, risk_list, risk_cap,
                                        n_tokens, pi_ws, ce_ws);
}